// Round 10
// baseline (5905.851 us; speedup 1.0000x reference)
//
#include <hip/hip_runtime.h>
#include <hip/hip_bf16.h>
#include <math.h>

#define NC_DIM 8192
#define C_DIM 2048
#define NTOK 8192
#define EPS_RMS 1.1920929e-07f

typedef __bf16 bf16_t;
typedef __attribute__((ext_vector_type(8))) __bf16 bf16x8;
typedef __attribute__((ext_vector_type(4))) __bf16 bf16x4;
typedef __attribute__((ext_vector_type(4))) float f32x4;

__device__ __forceinline__ void gload_lds16(const void* g, void* l) {
    __builtin_amdgcn_global_load_lds(
        (const __attribute__((address_space(1))) void*)g,
        (__attribute__((address_space(3))) void*)l, 16, 0, 0);
}

// ---------------- fp32 -> bf16 conversion (W1, W2) ----------------
__global__ __launch_bounds__(256) void cvt_f32_bf16(const float* __restrict__ in,
                                                    bf16_t* __restrict__ out,
                                                    const int n4) {
    int i = blockIdx.x * 256 + threadIdx.x;
    const int stride = gridDim.x * 256;
    for (; i < n4; i += stride) {
        f32x4 v = ((const f32x4*)in)[i];
        bf16x4 bv;
        bv.x = (__bf16)v.x; bv.y = (__bf16)v.y; bv.z = (__bf16)v.z; bv.w = (__bf16)v.w;
        ((bf16x4*)out)[i] = bv;
    }
}

// ---------------- projection + per-token scalars ----------------
__global__ __launch_bounds__(256) void k_proj(
    const float* __restrict__ x,      // [NTOK][8192]
    const float* __restrict__ Wall,   // [32][8192]
    const float* __restrict__ ball,   // [32]
    const float* __restrict__ apre,
    const float* __restrict__ apost,
    const float* __restrict__ ares,
    const float* __restrict__ perm,   // [24][16]
    float* __restrict__ hpre_g,       // [NTOK][4]
    float* __restrict__ hpost_g,      // [NTOK][4]
    float* __restrict__ Hm_g)         // [NTOK][16]
{
    __shared__ __align__(16) bf16_t xs[32 * 264];
    __shared__ __align__(16) bf16_t wsl[32 * 264];
    __shared__ float dparts[4][32][32];
    __shared__ float ssq_s[32];
    __shared__ float Ps[384];

    const int t = threadIdx.x;
    const int lane = t & 63;
    const int w = t >> 6;
    const int tok0 = blockIdx.x * 32;

    for (int i = t; i < 384; i += 256) Ps[i] = perm[i];

    const int row = t >> 3;
    const int i8 = t & 7;

    const float* xrow = x + (size_t)(tok0 + row) * (size_t)NC_DIM;
    const float* wrow = Wall + (size_t)row * (size_t)NC_DIM;

    float ssq = 0.0f;
    f32x4 acc[2][2];
#pragma unroll
    for (int m = 0; m < 2; ++m)
#pragma unroll
        for (int n = 0; n < 2; ++n) acc[m][n] = (f32x4){0.f, 0.f, 0.f, 0.f};

    const int rsel = lane & 15;
    const int ko_base = (lane >> 4) * 8;

    for (int kt = 0; kt < NC_DIM; kt += 256) {
        __syncthreads();
#pragma unroll
        for (int q = 0; q < 8; ++q) {
            const int col = (i8 + q * 8) * 4;
            f32x4 v = *(const f32x4*)(xrow + kt + col);
            ssq += v.x * v.x + v.y * v.y + v.z * v.z + v.w * v.w;
            bf16x4 bv;
            bv.x = (__bf16)v.x; bv.y = (__bf16)v.y; bv.z = (__bf16)v.z; bv.w = (__bf16)v.w;
            *(bf16x4*)(xs + row * 264 + col) = bv;
            f32x4 u = *(const f32x4*)(wrow + kt + col);
            bf16x4 bu;
            bu.x = (__bf16)u.x; bu.y = (__bf16)u.y; bu.z = (__bf16)u.z; bu.w = (__bf16)u.w;
            *(bf16x4*)(wsl + row * 264 + col) = bu;
        }
        __syncthreads();
#pragma unroll
        for (int ks = 0; ks < 2; ++ks) {
            const int ko = w * 64 + ks * 32 + ko_base;
            bf16x8 a0 = *(const bf16x8*)(xs + rsel * 264 + ko);
            bf16x8 a1 = *(const bf16x8*)(xs + (16 + rsel) * 264 + ko);
            bf16x8 b0 = *(const bf16x8*)(wsl + rsel * 264 + ko);
            bf16x8 b1 = *(const bf16x8*)(wsl + (16 + rsel) * 264 + ko);
            acc[0][0] = __builtin_amdgcn_mfma_f32_16x16x32_bf16(a0, b0, acc[0][0], 0, 0, 0);
            acc[0][1] = __builtin_amdgcn_mfma_f32_16x16x32_bf16(a0, b1, acc[0][1], 0, 0, 0);
            acc[1][0] = __builtin_amdgcn_mfma_f32_16x16x32_bf16(a1, b0, acc[1][0], 0, 0, 0);
            acc[1][1] = __builtin_amdgcn_mfma_f32_16x16x32_bf16(a1, b1, acc[1][1], 0, 0, 0);
        }
    }

    ssq += __shfl_xor(ssq, 1);
    ssq += __shfl_xor(ssq, 2);
    ssq += __shfl_xor(ssq, 4);
    if (i8 == 0) ssq_s[row] = ssq;

    const int cr = (lane >> 4) * 4;
#pragma unroll
    for (int m = 0; m < 2; ++m)
#pragma unroll
        for (int n = 0; n < 2; ++n)
#pragma unroll
            for (int j = 0; j < 4; ++j)
                dparts[w][m * 16 + cr + j][n * 16 + rsel] = acc[m][n][j];
    __syncthreads();

    if (t < 32) {
        const int g = tok0 + t;
        const float rinv = rsqrtf(ssq_s[t] * (1.0f / (float)NC_DIM) + EPS_RMS);
        float proj[32];
#pragma unroll
        for (int r = 0; r < 32; ++r)
            proj[r] = (dparts[0][t][r] + dparts[1][t][r] + dparts[2][t][r] + dparts[3][t][r]) * rinv;
        const float aP = apre[0], aQ = apost[0], aR = ares[0];
        float hp[4], hq[4];
#pragma unroll
        for (int i = 0; i < 4; ++i) {
            hp[i] = 1.0f / (1.0f + expf(-(aP * proj[i] + __ldg(&ball[i]))));
            hq[i] = 2.0f / (1.0f + expf(-(aQ * proj[4 + i] + __ldg(&ball[4 + i]))));
        }
        float zb[24];
        float mx = -1e30f;
#pragma unroll
        for (int p = 0; p < 24; ++p) {
            zb[p] = aR * proj[8 + p] + __ldg(&ball[8 + p]);
            mx = fmaxf(mx, zb[p]);
        }
        float s = 0.f;
#pragma unroll
        for (int p = 0; p < 24; ++p) { zb[p] = expf(zb[p] - mx); s += zb[p]; }
        const float is = 1.0f / s;
        float Hr[16];
#pragma unroll
        for (int idx = 0; idx < 16; ++idx) Hr[idx] = 0.f;
#pragma unroll
        for (int p = 0; p < 24; ++p) {
            const float a = zb[p] * is;
#pragma unroll
            for (int idx = 0; idx < 16; ++idx) Hr[idx] += a * Ps[p * 16 + idx];
        }
#pragma unroll
        for (int i = 0; i < 4; ++i) {
            hpre_g[(size_t)g * 4 + i] = hp[i];
            hpost_g[(size_t)g * 4 + i] = hq[i];
#pragma unroll
            for (int j = 0; j < 4; ++j)
                Hm_g[(size_t)g * 16 + i * 4 + j] = Hr[i * 4 + j] - hq[i] * hp[j];
        }
    }
}

// ---------------- layer_input = sum_n h_pre[n] * x[n] -> bf16 ----------------
__global__ __launch_bounds__(256) void k_mix(
    const float* __restrict__ x,
    const float* __restrict__ hpre_g,
    bf16_t* __restrict__ li)
{
    __shared__ float hp[8][4];
    const int t = threadIdx.x;
    const size_t tok0 = (size_t)blockIdx.x * 8;
    if (t < 32) hp[t >> 2][t & 3] = hpre_g[tok0 * 4 + t];
    __syncthreads();
    const int tl = t >> 5;
    const int ci = (t & 31) * 4;
    const size_t g = tok0 + tl;
    const float* xb = x + g * (size_t)NC_DIM;
    bf16_t* lo = li + g * (size_t)C_DIM;
    const float h0 = hp[tl][0], h1 = hp[tl][1], h2 = hp[tl][2], h3 = hp[tl][3];
#pragma unroll
    for (int q = 0; q < 16; ++q) {
        const int c = ci + q * 128;
        f32x4 v0 = *(const f32x4*)(xb + c);
        f32x4 v1 = *(const f32x4*)(xb + 2048 + c);
        f32x4 v2 = *(const f32x4*)(xb + 4096 + c);
        f32x4 v3 = *(const f32x4*)(xb + 6144 + c);
        f32x4 r = h0 * v0 + h1 * v1 + h2 * v2 + h3 * v3;
        bf16x4 bv;
        bv.x = (__bf16)r.x; bv.y = (__bf16)r.y; bv.z = (__bf16)r.z; bv.w = (__bf16)r.w;
        *(bf16x4*)(lo + c) = bv;
    }
}

// ---------------- GEMM1: 512x512 tile, BK=32 (h = gelu(li@W1^T + b1)) -----
// Staging-traffic lever: tile area 4x larger than 256^2 -> delivered tile
// traffic halves (2GB -> 1GB) and staging-per-MFMA halves. 256 blocks =
// 1/CU. LDS = 2 slots x (A 32KB + B 32KB) = 128KB. One barrier per K-tile:
// stage(t+1)->slot^1 issued at tile start (lands under ~1500cy of compute),
// vmcnt(0)+barrier at end. Same swizzle/fragment conventions as 256^2 core.
__global__ __launch_bounds__(512, 2) void gemm512(
    const bf16_t* __restrict__ A,   // [M][K]
    const bf16_t* __restrict__ Bm,  // [N][K]
    const float* __restrict__ bias, // [N]
    bf16_t* __restrict__ Cout,      // [M][N]
    const int M, const int N, const int K)
{
    __shared__ __align__(16) char lds[131072];
    const int tid = threadIdx.x;
    const int lane = tid & 63;
    const int w = tid >> 6;
    const int wr = w >> 2;   // 0..1 (256 rows each)
    const int wc = w & 3;    // 0..3 (128 cols each)

    // bijective XCD-aware block swizzle (gridDim.x % 8 == 0)
    const int nbn = N >> 9;            // tiles along N
    const int cpx = gridDim.x >> 3;
    const int bid = blockIdx.x;
    const int swz = (bid & 7) * cpx + (bid >> 3);
    const long tm = (long)(swz / nbn) * 512;
    const long tn = (long)(swz % nbn) * 512;

    const int NT = K >> 5;   // K-tiles of 32

    const int rsel = lane & 15;
    const int ko = (lane >> 4) * 8;
    const int lane_off = rsel * 64 + ((ko ^ (((rsel >> 1) & 3) << 3)) << 1);

    // staging source offsets: 4 images of 8KB per operand (32KB part each)
    const char* Abytes = (const char*)A;
    const char* Bbytes = (const char*)Bm;
    size_t asrc[4], bsrc[4];
#pragma unroll
    for (int j = 0; j < 4; ++j) {
        const int d = j * 8192 + tid * 16;
        const int sub = d >> 10;            // 16-row subtile (0..31)
        const int rr = (d >> 6) & 15;
        const int kk = ((d & 63) >> 1) ^ (((rr >> 1) & 3) << 3);
        asrc[j] = ((size_t)(tm + sub * 16 + rr) * K + kk) * 2;
        bsrc[j] = ((size_t)(tn + sub * 16 + rr) * K + kk) * 2;
    }

    auto stage = [&](int tile, int slot) {
        const int tt = tile < NT ? tile : NT - 1;
        const size_t koff = (size_t)tt * 64;   // 32 elems * 2B
        char* da = lds + slot * 65536 + tid * 16;
        char* db = lds + slot * 65536 + 32768 + tid * 16;
#pragma unroll
        for (int j = 0; j < 4; ++j)
            gload_lds16(Abytes + asrc[j] + koff, da + j * 8192);
#pragma unroll
        for (int j = 0; j < 4; ++j)
            gload_lds16(Bbytes + bsrc[j] + koff, db + j * 8192);
    };

    f32x4 acc[16][8];
#pragma unroll
    for (int m = 0; m < 16; ++m)
#pragma unroll
        for (int n = 0; n < 8; ++n) acc[m][n] = (f32x4){0.f, 0.f, 0.f, 0.f};

    bf16x8 aR[8], bR[8];

    // ---- prologue ----
    stage(0, 0);
    asm volatile("s_waitcnt vmcnt(0)" ::: "memory");
    __builtin_amdgcn_s_barrier();

    for (int t = 0; t < NT; ++t) {
        const int s = t & 1;
        stage(t + 1, s ^ 1);            // issue early; lands under compute
        const char* aS = lds + s * 65536 + (wr * 16) * 1024;
        const char* bS = lds + s * 65536 + 32768 + (wc * 8) * 1024;
#pragma unroll
        for (int nf = 0; nf < 8; ++nf)
            bR[nf] = *(const bf16x8*)(bS + nf * 1024 + lane_off);
#pragma unroll
        for (int hf = 0; hf < 2; ++hf) {
#pragma unroll
            for (int mf = 0; mf < 8; ++mf)
                aR[mf] = *(const bf16x8*)(aS + (hf * 8 + mf) * 1024 + lane_off);
            __builtin_amdgcn_s_setprio(1);
#pragma unroll
            for (int mf = 0; mf < 8; ++mf)
#pragma unroll
                for (int nf = 0; nf < 8; ++nf)
                    acc[hf * 8 + mf][nf] = __builtin_amdgcn_mfma_f32_16x16x32_bf16(
                        aR[mf], bR[nf], acc[hf * 8 + mf][nf], 0, 0, 0);
            __builtin_amdgcn_s_setprio(0);
        }
        asm volatile("s_waitcnt vmcnt(0)" ::: "memory");
        __builtin_amdgcn_s_barrier();
    }

    // ---- epilogue: h = gelu(acc + bias) -> bf16 ----
#pragma unroll
    for (int hf = 0; hf < 2; ++hf)
#pragma unroll
        for (int mf = 0; mf < 8; ++mf) {
            const long rb = tm + wr * 256 + (hf * 8 + mf) * 16 + (lane >> 4) * 4;
#pragma unroll
            for (int nf = 0; nf < 8; ++nf) {
                const long cg = tn + wc * 128 + nf * 16 + rsel;
                const float bv = __ldg(&bias[cg]);
                const f32x4 v4 = acc[hf * 8 + mf][nf];
#pragma unroll
                for (int j = 0; j < 4; ++j) {
                    const float v = v4[j] + bv;
                    const float ge = 0.5f * v * (1.0f + erff(v * 0.70710678118654752f));
                    Cout[(size_t)(rb + j) * N + cg] = (__bf16)ge;
                }
            }
        }
}

// ---------------- GEMM2 (256^2, R4 core) + fused final remix epilogue ----
__global__ __launch_bounds__(512, 2) void gemm2f(
    const bf16_t* __restrict__ A,   // h [M][K]
    const bf16_t* __restrict__ Bm,  // W2 [N][K]
    const float* __restrict__ bias, // b2 [N]
    float* __restrict__ outp,       // [M][4][2048]
    const int M, const int N, const int K,
    const float* __restrict__ xg,
    const float* __restrict__ hpost_g,
    const float* __restrict__ Hm_g)
{
    __shared__ __align__(16) char lds[131072];
    const int tid = threadIdx.x;
    const int lane = tid & 63;
    const int w = tid >> 6;
    const int wr = w >> 2;   // 0..1
    const int wc = w & 3;    // 0..3

    const int nbn = N >> 8;
    const int cpx = gridDim.x >> 3;
    const int bid = blockIdx.x;
    const int swz = (bid & 7) * cpx + (bid >> 3);
    const long tm = (long)(swz / nbn) * 256;
    const long tn = (long)(swz % nbn) * 256;

    const int NT = K >> 6;   // K-tiles of 64

    const int rsel = lane & 15;
    const int ko = (lane >> 4) * 8;
    const int lane_off = rsel * 64 + ((ko ^ (((rsel >> 1) & 3) << 3)) << 1);

    const char* Abytes = (const char*)A;
    const char* Bbytes = (const char*)Bm;
    size_t asrc[2][2], bsrc[2][2];
#pragma unroll
    for (int i = 0; i < 2; ++i) {
        const int d = i * 8192 + tid * 16;
        {
            const int awr = d >> 13, rem = d & 8191;
            const int sub = rem >> 10, rs = sub >> 1, ksub = sub & 1;
            const int rr = (rem >> 6) & 15;
            const int kk = ((rem & 63) >> 1) ^ (((rr >> 1) & 3) << 3);
            const int k = ksub * 32 + kk;
#pragma unroll
            for (int mq = 0; mq < 2; ++mq) {
                const long grow = tm + awr * 128 + mq * 64 + rs * 16 + rr;
                asrc[mq][i] = ((size_t)grow * K + k) * 2;
            }
        }
        {
            const int bwc = d >> 12, rem = d & 4095;
            const int sub = rem >> 10, rs = sub >> 1, ksub = sub & 1;
            const int rr = (rem >> 6) & 15;
            const int kk = ((rem & 63) >> 1) ^ (((rr >> 1) & 3) << 3);
            const int k = ksub * 32 + kk;
#pragma unroll
            for (int np = 0; np < 2; ++np) {
                const long grow = tn + bwc * 64 + np * 32 + rs * 16 + rr;
                bsrc[np][i] = ((size_t)grow * K + k) * 2;
            }
        }
    }

    auto stageA = [&](int mq, int tile, int slot) {
        const int tt = tile < NT ? tile : NT - 1;
        char* dst = lds + slot * 65536 + mq * 16384 + w * 1024;
        gload_lds16(Abytes + asrc[mq][0] + (size_t)tt * 128, dst);
        gload_lds16(Abytes + asrc[mq][1] + (size_t)tt * 128, dst + 8192);
    };
    auto stageB = [&](int np, int tile, int slot) {
        const int tt = tile < NT ? tile : NT - 1;
        char* dst = lds + slot * 65536 + 32768 + np * 16384 + w * 1024;
        gload_lds16(Bbytes + bsrc[np][0] + (size_t)tt * 128, dst);
        gload_lds16(Bbytes + bsrc[np][1] + (size_t)tt * 128, dst + 8192);
    };

    const char* aB = lds + wr * 8192;
    const char* bB = lds + 32768 + wc * 4096;

    f32x4 acc[8][4];
#pragma unroll
    for (int m = 0; m < 8; ++m)
#pragma unroll
        for (int n = 0; n < 4; ++n) acc[m][n] = (f32x4){0.f, 0.f, 0.f, 0.f};

    bf16x8 aR[4][2], b01[2][2], b23[2][2];

    stageA(0, 0, 0); stageB(0, 0, 0); stageB(1, 0, 0); stageA(1, 0, 0);
    stageA(0, 1, 1); stageB(0, 1, 1); stageB(1, 1, 1);
    asm volatile("s_waitcnt vmcnt(6)" ::: "memory");
    __builtin_amdgcn_s_barrier();

    for (int t = 0; t < NT; ++t) {
        const int s = t & 1;
        const char* aS = aB + s * 65536;
        const char* bS = bB + s * 65536;
#pragma unroll
        for (int mf = 0; mf < 4; ++mf)
#pragma unroll
            for (int ks = 0; ks < 2; ++ks)
                aR[mf][ks] = *(const bf16x8*)(aS + (mf * 2 + ks) * 1024 + lane_off);
#pragma unroll
        for (int nf = 0; nf < 2; ++nf)
#pragma unroll
            for (int ks = 0; ks < 2; ++ks)
                b01[nf][ks] = *(const bf16x8*)(bS + (nf * 2 + ks) * 1024 + lane_off);
        stageA(1, t + 1, s ^ 1);
        __builtin_amdgcn_s_setprio(1);
#pragma unroll
        for (int mf = 0; mf < 4; ++mf)
#pragma unroll
            for (int nf = 0; nf < 2; ++nf)
#pragma unroll
                for (int ks = 0; ks < 2; ++ks)
                    acc[mf][nf] = __builtin_amdgcn_mfma_f32_16x16x32_bf16(aR[mf][ks], b01[nf][ks], acc[mf][nf], 0, 0, 0);
        __builtin_amdgcn_s_setprio(0);
        __builtin_amdgcn_s_barrier();
#pragma unroll
        for (int nf = 0; nf < 2; ++nf)
#pragma unroll
            for (int ks = 0; ks < 2; ++ks)
                b23[nf][ks] = *(const bf16x8*)(bS + 16384 + (nf * 2 + ks) * 1024 + lane_off);
        stageA(0, t + 2, s);
        __builtin_amdgcn_s_setprio(1);
#pragma unroll
        for (int mf = 0; mf < 4; ++mf)
#pragma unroll
            for (int nf = 0; nf < 2; ++nf)
#pragma unroll
                for (int ks = 0; ks < 2; ++ks)
                    acc[mf][2 + nf] = __builtin_amdgcn_mfma_f32_16x16x32_bf16(aR[mf][ks], b23[nf][ks], acc[mf][2 + nf], 0, 0, 0);
        __builtin_amdgcn_s_setprio(0);
        __builtin_amdgcn_s_barrier();
#pragma unroll
        for (int mf = 0; mf < 4; ++mf)
#pragma unroll
            for (int ks = 0; ks < 2; ++ks)
                aR[mf][ks] = *(const bf16x8*)(aS + 16384 + (mf * 2 + ks) * 1024 + lane_off);
        stageB(0, t + 2, s);
        __builtin_amdgcn_s_setprio(1);
#pragma unroll
        for (int mf = 0; mf < 4; ++mf)
#pragma unroll
            for (int nf = 0; nf < 2; ++nf)
#pragma unroll
                for (int ks = 0; ks < 2; ++ks)
                    acc[4 + mf][2 + nf] = __builtin_amdgcn_mfma_f32_16x16x32_bf16(aR[mf][ks], b23[nf][ks], acc[4 + mf][2 + nf], 0, 0, 0);
        __builtin_amdgcn_s_setprio(0);
        __builtin_amdgcn_s_barrier();
        stageB(1, t + 2, s);
        asm volatile("s_waitcnt vmcnt(6)" ::: "memory");
        __builtin_amdgcn_s_setprio(1);
#pragma unroll
        for (int mf = 0; mf < 4; ++mf)
#pragma unroll
            for (int nf = 0; nf < 2; ++nf)
#pragma unroll
                for (int ks = 0; ks < 2; ++ks)
                    acc[4 + mf][nf] = __builtin_amdgcn_mfma_f32_16x16x32_bf16(aR[mf][ks], b01[nf][ks], acc[4 + mf][nf], 0, 0, 0);
        __builtin_amdgcn_s_setprio(0);
        __builtin_amdgcn_s_barrier();
    }

    // fused final remix epilogue
#pragma unroll
    for (int mq = 0; mq < 2; ++mq)
#pragma unroll
        for (int mf = 0; mf < 4; ++mf) {
            const long rbase = tm + wr * 128 + mq * 64 + mf * 16 + (lane >> 4) * 4;
#pragma unroll
            for (int j = 0; j < 4; ++j) {
                const long tok = rbase + j;
                float H[16], hq[4];
#pragma unroll
                for (int z = 0; z < 16; ++z) H[z] = __ldg(&Hm_g[tok * 16 + z]);
#pragma unroll
                for (int z = 0; z < 4; ++z) hq[z] = __ldg(&hpost_g[tok * 4 + z]);
                const float* xrow = xg + (size_t)tok * (size_t)NC_DIM;
                float* orow = outp + (size_t)tok * (size_t)NC_DIM;
#pragma unroll
                for (int np = 0; np < 2; ++np)
#pragma unroll
                    for (int nf = 0; nf < 2; ++nf) {
                        const long cg = tn + wc * 64 + np * 32 + nf * 16 + rsel;
                        const float lo = acc[mq * 4 + mf][np * 2 + nf][j] + __ldg(&bias[cg]);
                        const float x0 = xrow[cg];
                        const float x1 = xrow[2048 + cg];
                        const float x2 = xrow[4096 + cg];
                        const float x3 = xrow[6144 + cg];
#pragma unroll
                        for (int i = 0; i < 4; ++i)
                            orow[i * 2048 + cg] =
                                H[i * 4 + 0] * x0 + H[i * 4 + 1] * x1 +
                                H[i * 4 + 2] * x2 + H[i * 4 + 3] * x3 + hq[i] * lo;
                    }
            }
        }
}

extern "C" void kernel_launch(void* const* d_in, const int* in_sizes, int n_in,
                              void* d_out, int out_size, void* d_ws, size_t ws_size,
                              hipStream_t stream) {
    const float* x     = (const float*)d_in[0];
    const float* Wall  = (const float*)d_in[1];
    const float* ball  = (const float*)d_in[2];
    const float* apre  = (const float*)d_in[3];
    const float* apost = (const float*)d_in[4];
    const float* ares  = (const float*)d_in[5];
    const float* W1    = (const float*)d_in[6];
    const float* b1    = (const float*)d_in[7];
    const float* W2    = (const float*)d_in[8];
    const float* b2    = (const float*)d_in[9];
    const float* perm  = (const float*)d_in[10];
    float* out = (float*)d_out;
    char* ws = (char*)d_ws;

    // workspace layout (bytes)
    bf16_t* W1b  = (bf16_t*)(ws);                  //  32 MB  [8192][2048]
    bf16_t* W2b  = (bf16_t*)(ws + 33554432ull);    //  32 MB  [2048][8192]
    bf16_t* li   = (bf16_t*)(ws + 67108864ull);    //  32 MB  [8192][2048]
    bf16_t* h    = (bf16_t*)(ws + 100663296ull);   // 128 MB  [8192][8192]
    float*  hpre = (float*)(ws + 301989888ull);    // 128 KB  [8192][4]
    float*  hpost= (float*)(ws + 302120960ull);    // 128 KB  [8192][4]
    float*  Hm   = (float*)(ws + 302252032ull);    // 512 KB  [8192][16]

    cvt_f32_bf16<<<2048, 256, 0, stream>>>(W1, W1b, 16777216 / 4);
    cvt_f32_bf16<<<2048, 256, 0, stream>>>(W2, W2b, 16777216 / 4);
    k_proj<<<256, 256, 0, stream>>>(x, Wall, ball, apre, apost, ares, perm, hpre, hpost, Hm);
    k_mix<<<1024, 256, 0, stream>>>(x, hpre, li);
    gemm512<<<256, 512, 0, stream>>>(li, W1b, b1, h, 8192, 8192, 2048);
    gemm2f<<<256, 512, 0, stream>>>(h, W2b, b2, out, 8192, 2048, 8192,
                                    x, hpost, Hm);
}

// Round 11
// 796.646 us; speedup vs baseline: 7.4134x; 7.4134x over previous
//
#include <hip/hip_runtime.h>
#include <hip/hip_bf16.h>
#include <math.h>

#define NC_DIM 8192
#define C_DIM 2048
#define NTOK 8192
#define EPS_RMS 1.1920929e-07f

typedef __bf16 bf16_t;
typedef __attribute__((ext_vector_type(8))) __bf16 bf16x8;
typedef __attribute__((ext_vector_type(4))) __bf16 bf16x4;
typedef __attribute__((ext_vector_type(4))) float f32x4;

__device__ __forceinline__ void gload_lds16(const void* g, void* l) {
    __builtin_amdgcn_global_load_lds(
        (const __attribute__((address_space(1))) void*)g,
        (__attribute__((address_space(3))) void*)l, 16, 0, 0);
}

// 2D-chunked XCD swizzle: nbm=32 bands of 4 tm-rows per XCD; within a chunk,
// consecutive blocks cover 4(tm)x8(tn) rectangles -> concurrent blocks on an
// XCD share A-band (L2/L3) and B-window (L3). Bijective for grid=1024
// (nbn=32) and grid=256 (nbn=8); requires nbm==32, nbn%8==0 or nbn==8.
__device__ __forceinline__ void tile_swz(int bid, long& tm, long& tn) {
    const int x8 = bid & 7;
    const int l = bid >> 3;
    tm = (long)(x8 * 4 + ((l >> 3) & 3)) * 256;
    tn = (long)((l >> 5) * 8 + (l & 7)) * 256;
}

// ---------------- fp32 -> bf16 conversion (W1, W2) ----------------
__global__ __launch_bounds__(256) void cvt_f32_bf16(const float* __restrict__ in,
                                                    bf16_t* __restrict__ out,
                                                    const int n4) {
    int i = blockIdx.x * 256 + threadIdx.x;
    const int stride = gridDim.x * 256;
    for (; i < n4; i += stride) {
        f32x4 v = ((const f32x4*)in)[i];
        bf16x4 bv;
        bv.x = (__bf16)v.x; bv.y = (__bf16)v.y; bv.z = (__bf16)v.z; bv.w = (__bf16)v.w;
        ((bf16x4*)out)[i] = bv;
    }
}

// ---------------- projection + per-token scalars + FUSED layer-input mix ---
__global__ __launch_bounds__(256) void k_proj(
    const float* __restrict__ x,      // [NTOK][8192]
    const float* __restrict__ Wall,   // [32][8192]
    const float* __restrict__ ball,   // [32]
    const float* __restrict__ apre,
    const float* __restrict__ apost,
    const float* __restrict__ ares,
    const float* __restrict__ perm,   // [24][16]
    float* __restrict__ hpost_g,      // [NTOK][4]
    float* __restrict__ Hm_g,         // [NTOK][16]
    bf16_t* __restrict__ li)          // [NTOK][2048]  (fused k_mix output)
{
    __shared__ __align__(16) bf16_t xs[32 * 264];
    __shared__ __align__(16) bf16_t wsl[32 * 264];
    __shared__ float dparts[4][32][32];
    __shared__ float ssq_s[32];
    __shared__ float Ps[384];
    __shared__ float hps[32][4];

    const int t = threadIdx.x;
    const int lane = t & 63;
    const int w = t >> 6;
    const int tok0 = blockIdx.x * 32;

    for (int i = t; i < 384; i += 256) Ps[i] = perm[i];

    const int row = t >> 3;
    const int i8 = t & 7;

    const float* xrow = x + (size_t)(tok0 + row) * (size_t)NC_DIM;
    const float* wrow = Wall + (size_t)row * (size_t)NC_DIM;

    float ssq = 0.0f;
    f32x4 acc[2][2];
#pragma unroll
    for (int m = 0; m < 2; ++m)
#pragma unroll
        for (int n = 0; n < 2; ++n) acc[m][n] = (f32x4){0.f, 0.f, 0.f, 0.f};

    const int rsel = lane & 15;
    const int ko_base = (lane >> 4) * 8;

    for (int kt = 0; kt < NC_DIM; kt += 256) {
        __syncthreads();
#pragma unroll
        for (int q = 0; q < 8; ++q) {
            const int col = (i8 + q * 8) * 4;
            f32x4 v = *(const f32x4*)(xrow + kt + col);
            ssq += v.x * v.x + v.y * v.y + v.z * v.z + v.w * v.w;
            bf16x4 bv;
            bv.x = (__bf16)v.x; bv.y = (__bf16)v.y; bv.z = (__bf16)v.z; bv.w = (__bf16)v.w;
            *(bf16x4*)(xs + row * 264 + col) = bv;
            f32x4 u = *(const f32x4*)(wrow + kt + col);
            bf16x4 bu;
            bu.x = (__bf16)u.x; bu.y = (__bf16)u.y; bu.z = (__bf16)u.z; bu.w = (__bf16)u.w;
            *(bf16x4*)(wsl + row * 264 + col) = bu;
        }
        __syncthreads();
#pragma unroll
        for (int ks = 0; ks < 2; ++ks) {
            const int ko = w * 64 + ks * 32 + ko_base;
            bf16x8 a0 = *(const bf16x8*)(xs + rsel * 264 + ko);
            bf16x8 a1 = *(const bf16x8*)(xs + (16 + rsel) * 264 + ko);
            bf16x8 b0 = *(const bf16x8*)(wsl + rsel * 264 + ko);
            bf16x8 b1 = *(const bf16x8*)(wsl + (16 + rsel) * 264 + ko);
            acc[0][0] = __builtin_amdgcn_mfma_f32_16x16x32_bf16(a0, b0, acc[0][0], 0, 0, 0);
            acc[0][1] = __builtin_amdgcn_mfma_f32_16x16x32_bf16(a0, b1, acc[0][1], 0, 0, 0);
            acc[1][0] = __builtin_amdgcn_mfma_f32_16x16x32_bf16(a1, b0, acc[1][0], 0, 0, 0);
            acc[1][1] = __builtin_amdgcn_mfma_f32_16x16x32_bf16(a1, b1, acc[1][1], 0, 0, 0);
        }
    }

    ssq += __shfl_xor(ssq, 1);
    ssq += __shfl_xor(ssq, 2);
    ssq += __shfl_xor(ssq, 4);
    if (i8 == 0) ssq_s[row] = ssq;

    const int cr = (lane >> 4) * 4;
#pragma unroll
    for (int m = 0; m < 2; ++m)
#pragma unroll
        for (int n = 0; n < 2; ++n)
#pragma unroll
            for (int j = 0; j < 4; ++j)
                dparts[w][m * 16 + cr + j][n * 16 + rsel] = acc[m][n][j];
    __syncthreads();

    if (t < 32) {
        const int g = tok0 + t;
        const float rinv = rsqrtf(ssq_s[t] * (1.0f / (float)NC_DIM) + EPS_RMS);
        float proj[32];
#pragma unroll
        for (int r = 0; r < 32; ++r)
            proj[r] = (dparts[0][t][r] + dparts[1][t][r] + dparts[2][t][r] + dparts[3][t][r]) * rinv;
        const float aP = apre[0], aQ = apost[0], aR = ares[0];
        float hp[4], hq[4];
#pragma unroll
        for (int i = 0; i < 4; ++i) {
            hp[i] = 1.0f / (1.0f + expf(-(aP * proj[i] + __ldg(&ball[i]))));
            hq[i] = 2.0f / (1.0f + expf(-(aQ * proj[4 + i] + __ldg(&ball[4 + i]))));
            hps[t][i] = hp[i];
        }
        float zb[24];
        float mx = -1e30f;
#pragma unroll
        for (int p = 0; p < 24; ++p) {
            zb[p] = aR * proj[8 + p] + __ldg(&ball[8 + p]);
            mx = fmaxf(mx, zb[p]);
        }
        float s = 0.f;
#pragma unroll
        for (int p = 0; p < 24; ++p) { zb[p] = expf(zb[p] - mx); s += zb[p]; }
        const float is = 1.0f / s;
        float Hr[16];
#pragma unroll
        for (int idx = 0; idx < 16; ++idx) Hr[idx] = 0.f;
#pragma unroll
        for (int p = 0; p < 24; ++p) {
            const float a = zb[p] * is;
#pragma unroll
            for (int idx = 0; idx < 16; ++idx) Hr[idx] += a * Ps[p * 16 + idx];
        }
#pragma unroll
        for (int i = 0; i < 4; ++i) {
            hpost_g[(size_t)g * 4 + i] = hq[i];
#pragma unroll
            for (int j = 0; j < 4; ++j)
                Hm_g[(size_t)g * 16 + i * 4 + j] = Hr[i * 4 + j] - hq[i] * hp[j];
        }
    }
    __syncthreads();

    // ---- fused k_mix: li[tok] = sum_n hpre[n] * x[tok, n*2048:...] ----
    // Re-reads the block's own x rows (L2/L3-hot from the pass above).
    const float h0 = hps[row][0], h1 = hps[row][1], h2 = hps[row][2], h3 = hps[row][3];
    bf16_t* lo = li + (size_t)(tok0 + row) * (size_t)C_DIM;
#pragma unroll 4
    for (int q = 0; q < 64; ++q) {
        const int c = (i8 + q * 8) * 4;
        f32x4 v0 = *(const f32x4*)(xrow + c);
        f32x4 v1 = *(const f32x4*)(xrow + 2048 + c);
        f32x4 v2 = *(const f32x4*)(xrow + 4096 + c);
        f32x4 v3 = *(const f32x4*)(xrow + 6144 + c);
        f32x4 r = h0 * v0 + h1 * v1 + h2 * v2 + h3 * v3;
        bf16x4 bv;
        bv.x = (__bf16)r.x; bv.y = (__bf16)r.y; bv.z = (__bf16)r.z; bv.w = (__bf16)r.w;
        *(bf16x4*)(lo + c) = bv;
    }
}

// ---------------- GEMM1 (256^2, R4 core): h = gelu(li@W1^T + b1) ----------
__global__ __launch_bounds__(512, 2) void gemm1k(
    const bf16_t* __restrict__ A,   // [M][K]
    const bf16_t* __restrict__ Bm,  // [N][K]
    const float* __restrict__ bias, // [N]
    bf16_t* __restrict__ Cout,
    const int M, const int N, const int K)
{
    __shared__ __align__(16) char lds[131072];
    const int tid = threadIdx.x;
    const int lane = tid & 63;
    const int w = tid >> 6;
    const int wr = w >> 2;
    const int wc = w & 3;

    long tm, tn;
    tile_swz(blockIdx.x, tm, tn);

    const int NT = K >> 6;

    const int rsel = lane & 15;
    const int ko = (lane >> 4) * 8;
    const int lane_off = rsel * 64 + ((ko ^ (((rsel >> 1) & 3) << 3)) << 1);

    const char* Abytes = (const char*)A;
    const char* Bbytes = (const char*)Bm;
    size_t asrc[2][2], bsrc[2][2];
#pragma unroll
    for (int i = 0; i < 2; ++i) {
        const int d = i * 8192 + tid * 16;
        {
            const int awr = d >> 13, rem = d & 8191;
            const int sub = rem >> 10, rs = sub >> 1, ksub = sub & 1;
            const int rr = (rem >> 6) & 15;
            const int kk = ((rem & 63) >> 1) ^ (((rr >> 1) & 3) << 3);
            const int k = ksub * 32 + kk;
#pragma unroll
            for (int mq = 0; mq < 2; ++mq) {
                const long grow = tm + awr * 128 + mq * 64 + rs * 16 + rr;
                asrc[mq][i] = ((size_t)grow * K + k) * 2;
            }
        }
        {
            const int bwc = d >> 12, rem = d & 4095;
            const int sub = rem >> 10, rs = sub >> 1, ksub = sub & 1;
            const int rr = (rem >> 6) & 15;
            const int kk = ((rem & 63) >> 1) ^ (((rr >> 1) & 3) << 3);
            const int k = ksub * 32 + kk;
#pragma unroll
            for (int np = 0; np < 2; ++np) {
                const long grow = tn + bwc * 64 + np * 32 + rs * 16 + rr;
                bsrc[np][i] = ((size_t)grow * K + k) * 2;
            }
        }
    }

    auto stageA = [&](int mq, int tile, int slot) {
        const int tt = tile < NT ? tile : NT - 1;
        char* dst = lds + slot * 65536 + mq * 16384 + w * 1024;
        gload_lds16(Abytes + asrc[mq][0] + (size_t)tt * 128, dst);
        gload_lds16(Abytes + asrc[mq][1] + (size_t)tt * 128, dst + 8192);
    };
    auto stageB = [&](int np, int tile, int slot) {
        const int tt = tile < NT ? tile : NT - 1;
        char* dst = lds + slot * 65536 + 32768 + np * 16384 + w * 1024;
        gload_lds16(Bbytes + bsrc[np][0] + (size_t)tt * 128, dst);
        gload_lds16(Bbytes + bsrc[np][1] + (size_t)tt * 128, dst + 8192);
    };

    const char* aB = lds + wr * 8192;
    const char* bB = lds + 32768 + wc * 4096;

    f32x4 acc[8][4];
#pragma unroll
    for (int m = 0; m < 8; ++m)
#pragma unroll
        for (int n = 0; n < 4; ++n) acc[m][n] = (f32x4){0.f, 0.f, 0.f, 0.f};

    bf16x8 aR[4][2], b01[2][2], b23[2][2];

    stageA(0, 0, 0); stageB(0, 0, 0); stageB(1, 0, 0); stageA(1, 0, 0);
    stageA(0, 1, 1); stageB(0, 1, 1); stageB(1, 1, 1);
    asm volatile("s_waitcnt vmcnt(6)" ::: "memory");
    __builtin_amdgcn_s_barrier();

    for (int t = 0; t < NT; ++t) {
        const int s = t & 1;
        const char* aS = aB + s * 65536;
        const char* bS = bB + s * 65536;
#pragma unroll
        for (int mf = 0; mf < 4; ++mf)
#pragma unroll
            for (int ks = 0; ks < 2; ++ks)
                aR[mf][ks] = *(const bf16x8*)(aS + (mf * 2 + ks) * 1024 + lane_off);
#pragma unroll
        for (int nf = 0; nf < 2; ++nf)
#pragma unroll
            for (int ks = 0; ks < 2; ++ks)
                b01[nf][ks] = *(const bf16x8*)(bS + (nf * 2 + ks) * 1024 + lane_off);
        stageA(1, t + 1, s ^ 1);
        __builtin_amdgcn_s_setprio(1);
#pragma unroll
        for (int mf = 0; mf < 4; ++mf)
#pragma unroll
            for (int nf = 0; nf < 2; ++nf)
#pragma unroll
                for (int ks = 0; ks < 2; ++ks)
                    acc[mf][nf] = __builtin_amdgcn_mfma_f32_16x16x32_bf16(aR[mf][ks], b01[nf][ks], acc[mf][nf], 0, 0, 0);
        __builtin_amdgcn_s_setprio(0);
        __builtin_amdgcn_s_barrier();
#pragma unroll
        for (int nf = 0; nf < 2; ++nf)
#pragma unroll
            for (int ks = 0; ks < 2; ++ks)
                b23[nf][ks] = *(const bf16x8*)(bS + 16384 + (nf * 2 + ks) * 1024 + lane_off);
        stageA(0, t + 2, s);
        __builtin_amdgcn_s_setprio(1);
#pragma unroll
        for (int mf = 0; mf < 4; ++mf)
#pragma unroll
            for (int nf = 0; nf < 2; ++nf)
#pragma unroll
                for (int ks = 0; ks < 2; ++ks)
                    acc[mf][2 + nf] = __builtin_amdgcn_mfma_f32_16x16x32_bf16(aR[mf][ks], b23[nf][ks], acc[mf][2 + nf], 0, 0, 0);
        __builtin_amdgcn_s_setprio(0);
        __builtin_amdgcn_s_barrier();
#pragma unroll
        for (int mf = 0; mf < 4; ++mf)
#pragma unroll
            for (int ks = 0; ks < 2; ++ks)
                aR[mf][ks] = *(const bf16x8*)(aS + 16384 + (mf * 2 + ks) * 1024 + lane_off);
        stageB(0, t + 2, s);
        __builtin_amdgcn_s_setprio(1);
#pragma unroll
        for (int mf = 0; mf < 4; ++mf)
#pragma unroll
            for (int nf = 0; nf < 2; ++nf)
#pragma unroll
                for (int ks = 0; ks < 2; ++ks)
                    acc[4 + mf][2 + nf] = __builtin_amdgcn_mfma_f32_16x16x32_bf16(aR[mf][ks], b23[nf][ks], acc[4 + mf][2 + nf], 0, 0, 0);
        __builtin_amdgcn_s_setprio(0);
        __builtin_amdgcn_s_barrier();
        stageB(1, t + 2, s);
        asm volatile("s_waitcnt vmcnt(6)" ::: "memory");
        __builtin_amdgcn_s_setprio(1);
#pragma unroll
        for (int mf = 0; mf < 4; ++mf)
#pragma unroll
            for (int nf = 0; nf < 2; ++nf)
#pragma unroll
                for (int ks = 0; ks < 2; ++ks)
                    acc[4 + mf][nf] = __builtin_amdgcn_mfma_f32_16x16x32_bf16(aR[mf][ks], b01[nf][ks], acc[4 + mf][nf], 0, 0, 0);
        __builtin_amdgcn_s_setprio(0);
        __builtin_amdgcn_s_barrier();
    }

#pragma unroll
    for (int mq = 0; mq < 2; ++mq)
#pragma unroll
        for (int mf = 0; mf < 4; ++mf) {
            const long rbase = tm + wr * 128 + mq * 64 + mf * 16 + (lane >> 4) * 4;
#pragma unroll
            for (int np = 0; np < 2; ++np)
#pragma unroll
                for (int nf = 0; nf < 2; ++nf) {
                    const long cg = tn + wc * 64 + np * 32 + nf * 16 + rsel;
                    const float bv = __ldg(&bias[cg]);
                    const f32x4 v4 = acc[mq * 4 + mf][np * 2 + nf];
#pragma unroll
                    for (int j = 0; j < 4; ++j) {
                        const float v = v4[j] + bv;
                        const float ge = 0.5f * v * (1.0f + erff(v * 0.70710678118654752f));
                        Cout[(size_t)(rbase + j) * N + cg] = (__bf16)ge;
                    }
                }
        }
}

// ---------------- GEMM2 (256^2, R4 core) + fused final remix epilogue ----
__global__ __launch_bounds__(512, 2) void gemm2f(
    const bf16_t* __restrict__ A,   // h [M][K]
    const bf16_t* __restrict__ Bm,  // W2 [N][K]
    const float* __restrict__ bias, // b2 [N]
    float* __restrict__ outp,       // [M][4][2048]
    const int M, const int N, const int K,
    const float* __restrict__ xg,
    const float* __restrict__ hpost_g,
    const float* __restrict__ Hm_g)
{
    __shared__ __align__(16) char lds[131072];
    const int tid = threadIdx.x;
    const int lane = tid & 63;
    const int w = tid >> 6;
    const int wr = w >> 2;
    const int wc = w & 3;

    long tm, tn;
    tile_swz(blockIdx.x, tm, tn);

    const int NT = K >> 6;

    const int rsel = lane & 15;
    const int ko = (lane >> 4) * 8;
    const int lane_off = rsel * 64 + ((ko ^ (((rsel >> 1) & 3) << 3)) << 1);

    const char* Abytes = (const char*)A;
    const char* Bbytes = (const char*)Bm;
    size_t asrc[2][2], bsrc[2][2];
#pragma unroll
    for (int i = 0; i < 2; ++i) {
        const int d = i * 8192 + tid * 16;
        {
            const int awr = d >> 13, rem = d & 8191;
            const int sub = rem >> 10, rs = sub >> 1, ksub = sub & 1;
            const int rr = (rem >> 6) & 15;
            const int kk = ((rem & 63) >> 1) ^ (((rr >> 1) & 3) << 3);
            const int k = ksub * 32 + kk;
#pragma unroll
            for (int mq = 0; mq < 2; ++mq) {
                const long grow = tm + awr * 128 + mq * 64 + rs * 16 + rr;
                asrc[mq][i] = ((size_t)grow * K + k) * 2;
            }
        }
        {
            const int bwc = d >> 12, rem = d & 4095;
            const int sub = rem >> 10, rs = sub >> 1, ksub = sub & 1;
            const int rr = (rem >> 6) & 15;
            const int kk = ((rem & 63) >> 1) ^ (((rr >> 1) & 3) << 3);
            const int k = ksub * 32 + kk;
#pragma unroll
            for (int np = 0; np < 2; ++np) {
                const long grow = tn + bwc * 64 + np * 32 + rs * 16 + rr;
                bsrc[np][i] = ((size_t)grow * K + k) * 2;
            }
        }
    }

    auto stageA = [&](int mq, int tile, int slot) {
        const int tt = tile < NT ? tile : NT - 1;
        char* dst = lds + slot * 65536 + mq * 16384 + w * 1024;
        gload_lds16(Abytes + asrc[mq][0] + (size_t)tt * 128, dst);
        gload_lds16(Abytes + asrc[mq][1] + (size_t)tt * 128, dst + 8192);
    };
    auto stageB = [&](int np, int tile, int slot) {
        const int tt = tile < NT ? tile : NT - 1;
        char* dst = lds + slot * 65536 + 32768 + np * 16384 + w * 1024;
        gload_lds16(Bbytes + bsrc[np][0] + (size_t)tt * 128, dst);
        gload_lds16(Bbytes + bsrc[np][1] + (size_t)tt * 128, dst + 8192);
    };

    const char* aB = lds + wr * 8192;
    const char* bB = lds + 32768 + wc * 4096;

    f32x4 acc[8][4];
#pragma unroll
    for (int m = 0; m < 8; ++m)
#pragma unroll
        for (int n = 0; n < 4; ++n) acc[m][n] = (f32x4){0.f, 0.f, 0.f, 0.f};

    bf16x8 aR[4][2], b01[2][2], b23[2][2];

    stageA(0, 0, 0); stageB(0, 0, 0); stageB(1, 0, 0); stageA(1, 0, 0);
    stageA(0, 1, 1); stageB(0, 1, 1); stageB(1, 1, 1);
    asm volatile("s_waitcnt vmcnt(6)" ::: "memory");
    __builtin_amdgcn_s_barrier();

    for (int t = 0; t < NT; ++t) {
        const int s = t & 1;
        const char* aS = aB + s * 65536;
        const char* bS = bB + s * 65536;
#pragma unroll
        for (int mf = 0; mf < 4; ++mf)
#pragma unroll
            for (int ks = 0; ks < 2; ++ks)
                aR[mf][ks] = *(const bf16x8*)(aS + (mf * 2 + ks) * 1024 + lane_off);
#pragma unroll
        for (int nf = 0; nf < 2; ++nf)
#pragma unroll
            for (int ks = 0; ks < 2; ++ks)
                b01[nf][ks] = *(const bf16x8*)(bS + (nf * 2 + ks) * 1024 + lane_off);
        stageA(1, t + 1, s ^ 1);
        __builtin_amdgcn_s_setprio(1);
#pragma unroll
        for (int mf = 0; mf < 4; ++mf)
#pragma unroll
            for (int nf = 0; nf < 2; ++nf)
#pragma unroll
                for (int ks = 0; ks < 2; ++ks)
                    acc[mf][nf] = __builtin_amdgcn_mfma_f32_16x16x32_bf16(aR[mf][ks], b01[nf][ks], acc[mf][nf], 0, 0, 0);
        __builtin_amdgcn_s_setprio(0);
        __builtin_amdgcn_s_barrier();
#pragma unroll
        for (int nf = 0; nf < 2; ++nf)
#pragma unroll
            for (int ks = 0; ks < 2; ++ks)
                b23[nf][ks] = *(const bf16x8*)(bS + 16384 + (nf * 2 + ks) * 1024 + lane_off);
        stageA(0, t + 2, s);
        __builtin_amdgcn_s_setprio(1);
#pragma unroll
        for (int mf = 0; mf < 4; ++mf)
#pragma unroll
            for (int nf = 0; nf < 2; ++nf)
#pragma unroll
                for (int ks = 0; ks < 2; ++ks)
                    acc[mf][2 + nf] = __builtin_amdgcn_mfma_f32_16x16x32_bf16(aR[mf][ks], b23[nf][ks], acc[mf][2 + nf], 0, 0, 0);
        __builtin_amdgcn_s_setprio(0);
        __builtin_amdgcn_s_barrier();
#pragma unroll
        for (int mf = 0; mf < 4; ++mf)
#pragma unroll
            for (int ks = 0; ks < 2; ++ks)
                aR[mf][ks] = *(const bf16x8*)(aS + 16384 + (mf * 2 + ks) * 1024 + lane_off);
        stageB(0, t + 2, s);
        __builtin_amdgcn_s_setprio(1);
#pragma unroll
        for (int mf = 0; mf < 4; ++mf)
#pragma unroll
            for (int nf = 0; nf < 2; ++nf)
#pragma unroll
                for (int ks = 0; ks < 2; ++ks)
                    acc[4 + mf][2 + nf] = __builtin_amdgcn_mfma_f32_16x16x32_bf16(aR[mf][ks], b23[nf][ks], acc[4 + mf][2 + nf], 0, 0, 0);
        __builtin_amdgcn_s_setprio(0);
        __builtin_amdgcn_s_barrier();
        stageB(1, t + 2, s);
        asm volatile("s_waitcnt vmcnt(6)" ::: "memory");
        __builtin_amdgcn_s_setprio(1);
#pragma unroll
        for (int mf = 0; mf < 4; ++mf)
#pragma unroll
            for (int nf = 0; nf < 2; ++nf)
#pragma unroll
                for (int ks = 0; ks < 2; ++ks)
                    acc[4 + mf][nf] = __builtin_amdgcn_mfma_f32_16x16x32_bf16(aR[mf][ks], b01[nf][ks], acc[4 + mf][nf], 0, 0, 0);
        __builtin_amdgcn_s_setprio(0);
        __builtin_amdgcn_s_barrier();
    }

    // fused final remix epilogue (non-temporal out stores: out never re-read)
#pragma unroll
    for (int mq = 0; mq < 2; ++mq)
#pragma unroll
        for (int mf = 0; mf < 4; ++mf) {
            const long rbase = tm + wr * 128 + mq * 64 + mf * 16 + (lane >> 4) * 4;
#pragma unroll
            for (int j = 0; j < 4; ++j) {
                const long tok = rbase + j;
                float H[16], hq[4];
#pragma unroll
                for (int z = 0; z < 16; ++z) H[z] = __ldg(&Hm_g[tok * 16 + z]);
#pragma unroll
                for (int z = 0; z < 4; ++z) hq[z] = __ldg(&hpost_g[tok * 4 + z]);
                const float* xrow = xg + (size_t)tok * (size_t)NC_DIM;
                float* orow = outp + (size_t)tok * (size_t)NC_DIM;
#pragma unroll
                for (int np = 0; np < 2; ++np)
#pragma unroll
                    for (int nf = 0; nf < 2; ++nf) {
                        const long cg = tn + wc * 64 + np * 32 + nf * 16 + rsel;
                        const float lo = acc[mq * 4 + mf][np * 2 + nf][j] + __ldg(&bias[cg]);
                        const float x0 = xrow[cg];
                        const float x1 = xrow[2048 + cg];
                        const float x2 = xrow[4096 + cg];
                        const float x3 = xrow[6144 + cg];
#pragma unroll
                        for (int i = 0; i < 4; ++i) {
                            const float r =
                                H[i * 4 + 0] * x0 + H[i * 4 + 1] * x1 +
                                H[i * 4 + 2] * x2 + H[i * 4 + 3] * x3 + hq[i] * lo;
                            __builtin_nontemporal_store(r, &orow[i * 2048 + cg]);
                        }
                    }
            }
        }
}

extern "C" void kernel_launch(void* const* d_in, const int* in_sizes, int n_in,
                              void* d_out, int out_size, void* d_ws, size_t ws_size,
                              hipStream_t stream) {
    const float* x     = (const float*)d_in[0];
    const float* Wall  = (const float*)d_in[1];
    const float* ball  = (const float*)d_in[2];
    const float* apre  = (const float*)d_in[3];
    const float* apost = (const float*)d_in[4];
    const float* ares  = (const float*)d_in[5];
    const float* W1    = (const float*)d_in[6];
    const float* b1    = (const float*)d_in[7];
    const float* W2    = (const float*)d_in[8];
    const float* b2    = (const float*)d_in[9];
    const float* perm  = (const float*)d_in[10];
    float* out = (float*)d_out;
    char* ws = (char*)d_ws;

    // workspace layout (bytes)
    bf16_t* W1b  = (bf16_t*)(ws);                  //  32 MB  [8192][2048]
    bf16_t* W2b  = (bf16_t*)(ws + 33554432ull);    //  32 MB  [2048][8192]
    bf16_t* li   = (bf16_t*)(ws + 67108864ull);    //  32 MB  [8192][2048]
    bf16_t* h    = (bf16_t*)(ws + 100663296ull);   // 128 MB  [8192][8192]
    float*  hpost= (float*)(ws + 302120960ull);    // 128 KB  [8192][4]
    float*  Hm   = (float*)(ws + 302252032ull);    // 512 KB  [8192][16]

    cvt_f32_bf16<<<2048, 256, 0, stream>>>(W1, W1b, 16777216 / 4);
    cvt_f32_bf16<<<2048, 256, 0, stream>>>(W2, W2b, 16777216 / 4);
    k_proj<<<256, 256, 0, stream>>>(x, Wall, ball, apre, apost, ares, perm, hpost, Hm, li);
    gemm1k<<<1024, 512, 0, stream>>>(li, W1b, b1, h, 8192, 8192, 2048);
    gemm2f<<<256, 512, 0, stream>>>(h, W2b, b2, out, 8192, 2048, 8192,
                                    x, hpost, Hm);
}

// Round 12
// 785.851 us; speedup vs baseline: 7.5152x; 1.0137x over previous
//
#include <hip/hip_runtime.h>
#include <hip/hip_bf16.h>
#include <math.h>

#define NC_DIM 8192
#define C_DIM 2048
#define NTOK 8192
#define EPS_RMS 1.1920929e-07f

typedef __bf16 bf16_t;
typedef __attribute__((ext_vector_type(8))) __bf16 bf16x8;
typedef __attribute__((ext_vector_type(4))) __bf16 bf16x4;
typedef __attribute__((ext_vector_type(4))) float f32x4;

__device__ __forceinline__ void gload_lds16(const void* g, void* l) {
    __builtin_amdgcn_global_load_lds(
        (const __attribute__((address_space(1))) void*)g,
        (__attribute__((address_space(3))) void*)l, 16, 0, 0);
}

// 2D-chunked XCD swizzle: each XCD owns a 4-row tm band; consecutive blocks
// cover 4(tm)x8(tn) rectangles. Bijective for grid=1024 and grid=256.
__device__ __forceinline__ void tile_swz(int bid, long& tm, long& tn) {
    const int x8 = bid & 7;
    const int l = bid >> 3;
    tm = (long)(x8 * 4 + ((l >> 3) & 3)) * 256;
    tn = (long)((l >> 5) * 8 + (l & 7)) * 256;
}

// ---------------- fp32 -> bf16 conversion (W1, W2) ----------------
__global__ __launch_bounds__(256) void cvt_f32_bf16(const float* __restrict__ in,
                                                    bf16_t* __restrict__ out,
                                                    const int n4) {
    int i = blockIdx.x * 256 + threadIdx.x;
    const int stride = gridDim.x * 256;
    for (; i < n4; i += stride) {
        f32x4 v = ((const f32x4*)in)[i];
        bf16x4 bv;
        bv.x = (__bf16)v.x; bv.y = (__bf16)v.y; bv.z = (__bf16)v.z; bv.w = (__bf16)v.w;
        ((bf16x4*)out)[i] = bv;
    }
}

// ---------------- projection + per-token scalars + FUSED layer-input mix ---
__global__ __launch_bounds__(256) void k_proj(
    const float* __restrict__ x,      // [NTOK][8192]
    const float* __restrict__ Wall,   // [32][8192]
    const float* __restrict__ ball,   // [32]
    const float* __restrict__ apre,
    const float* __restrict__ apost,
    const float* __restrict__ ares,
    const float* __restrict__ perm,   // [24][16]
    float* __restrict__ hpost_g,      // [NTOK][4]
    float* __restrict__ Hm_g,         // [NTOK][16]
    bf16_t* __restrict__ li)          // [NTOK][2048]  (fused k_mix output)
{
    __shared__ __align__(16) bf16_t xs[32 * 264];
    __shared__ __align__(16) bf16_t wsl[32 * 264];
    __shared__ float dparts[4][32][32];
    __shared__ float ssq_s[32];
    __shared__ float Ps[384];
    __shared__ float hps[32][4];

    const int t = threadIdx.x;
    const int lane = t & 63;
    const int w = t >> 6;
    const int tok0 = blockIdx.x * 32;

    for (int i = t; i < 384; i += 256) Ps[i] = perm[i];

    const int row = t >> 3;
    const int i8 = t & 7;

    const float* xrow = x + (size_t)(tok0 + row) * (size_t)NC_DIM;
    const float* wrow = Wall + (size_t)row * (size_t)NC_DIM;

    float ssq = 0.0f;
    f32x4 acc[2][2];
#pragma unroll
    for (int m = 0; m < 2; ++m)
#pragma unroll
        for (int n = 0; n < 2; ++n) acc[m][n] = (f32x4){0.f, 0.f, 0.f, 0.f};

    const int rsel = lane & 15;
    const int ko_base = (lane >> 4) * 8;

    for (int kt = 0; kt < NC_DIM; kt += 256) {
        __syncthreads();
#pragma unroll
        for (int q = 0; q < 8; ++q) {
            const int col = (i8 + q * 8) * 4;
            f32x4 v = *(const f32x4*)(xrow + kt + col);
            ssq += v.x * v.x + v.y * v.y + v.z * v.z + v.w * v.w;
            bf16x4 bv;
            bv.x = (__bf16)v.x; bv.y = (__bf16)v.y; bv.z = (__bf16)v.z; bv.w = (__bf16)v.w;
            *(bf16x4*)(xs + row * 264 + col) = bv;
            f32x4 u = *(const f32x4*)(wrow + kt + col);
            bf16x4 bu;
            bu.x = (__bf16)u.x; bu.y = (__bf16)u.y; bu.z = (__bf16)u.z; bu.w = (__bf16)u.w;
            *(bf16x4*)(wsl + row * 264 + col) = bu;
        }
        __syncthreads();
#pragma unroll
        for (int ks = 0; ks < 2; ++ks) {
            const int ko = w * 64 + ks * 32 + ko_base;
            bf16x8 a0 = *(const bf16x8*)(xs + rsel * 264 + ko);
            bf16x8 a1 = *(const bf16x8*)(xs + (16 + rsel) * 264 + ko);
            bf16x8 b0 = *(const bf16x8*)(wsl + rsel * 264 + ko);
            bf16x8 b1 = *(const bf16x8*)(wsl + (16 + rsel) * 264 + ko);
            acc[0][0] = __builtin_amdgcn_mfma_f32_16x16x32_bf16(a0, b0, acc[0][0], 0, 0, 0);
            acc[0][1] = __builtin_amdgcn_mfma_f32_16x16x32_bf16(a0, b1, acc[0][1], 0, 0, 0);
            acc[1][0] = __builtin_amdgcn_mfma_f32_16x16x32_bf16(a1, b0, acc[1][0], 0, 0, 0);
            acc[1][1] = __builtin_amdgcn_mfma_f32_16x16x32_bf16(a1, b1, acc[1][1], 0, 0, 0);
        }
    }

    ssq += __shfl_xor(ssq, 1);
    ssq += __shfl_xor(ssq, 2);
    ssq += __shfl_xor(ssq, 4);
    if (i8 == 0) ssq_s[row] = ssq;

    const int cr = (lane >> 4) * 4;
#pragma unroll
    for (int m = 0; m < 2; ++m)
#pragma unroll
        for (int n = 0; n < 2; ++n)
#pragma unroll
            for (int j = 0; j < 4; ++j)
                dparts[w][m * 16 + cr + j][n * 16 + rsel] = acc[m][n][j];
    __syncthreads();

    if (t < 32) {
        const int g = tok0 + t;
        const float rinv = rsqrtf(ssq_s[t] * (1.0f / (float)NC_DIM) + EPS_RMS);
        float proj[32];
#pragma unroll
        for (int r = 0; r < 32; ++r)
            proj[r] = (dparts[0][t][r] + dparts[1][t][r] + dparts[2][t][r] + dparts[3][t][r]) * rinv;
        const float aP = apre[0], aQ = apost[0], aR = ares[0];
        float hp[4], hq[4];
#pragma unroll
        for (int i = 0; i < 4; ++i) {
            hp[i] = 1.0f / (1.0f + expf(-(aP * proj[i] + __ldg(&ball[i]))));
            hq[i] = 2.0f / (1.0f + expf(-(aQ * proj[4 + i] + __ldg(&ball[4 + i]))));
            hps[t][i] = hp[i];
        }
        float zb[24];
        float mx = -1e30f;
#pragma unroll
        for (int p = 0; p < 24; ++p) {
            zb[p] = aR * proj[8 + p] + __ldg(&ball[8 + p]);
            mx = fmaxf(mx, zb[p]);
        }
        float s = 0.f;
#pragma unroll
        for (int p = 0; p < 24; ++p) { zb[p] = expf(zb[p] - mx); s += zb[p]; }
        const float is = 1.0f / s;
        float Hr[16];
#pragma unroll
        for (int idx = 0; idx < 16; ++idx) Hr[idx] = 0.f;
#pragma unroll
        for (int p = 0; p < 24; ++p) {
            const float a = zb[p] * is;
#pragma unroll
            for (int idx = 0; idx < 16; ++idx) Hr[idx] += a * Ps[p * 16 + idx];
        }
#pragma unroll
        for (int i = 0; i < 4; ++i) {
            hpost_g[(size_t)g * 4 + i] = hq[i];
#pragma unroll
            for (int j = 0; j < 4; ++j)
                Hm_g[(size_t)g * 16 + i * 4 + j] = Hr[i * 4 + j] - hq[i] * hp[j];
        }
    }
    __syncthreads();

    // ---- fused k_mix: li[tok] = sum_n hpre[n] * x[tok, n*2048:...] ----
    const float h0 = hps[row][0], h1 = hps[row][1], h2 = hps[row][2], h3 = hps[row][3];
    bf16_t* lo = li + (size_t)(tok0 + row) * (size_t)C_DIM;
#pragma unroll 4
    for (int q = 0; q < 64; ++q) {
        const int c = (i8 + q * 8) * 4;
        f32x4 v0 = *(const f32x4*)(xrow + c);
        f32x4 v1 = *(const f32x4*)(xrow + 2048 + c);
        f32x4 v2 = *(const f32x4*)(xrow + 4096 + c);
        f32x4 v3 = *(const f32x4*)(xrow + 6144 + c);
        f32x4 r = h0 * v0 + h1 * v1 + h2 * v2 + h3 * v3;
        bf16x4 bv;
        bv.x = (__bf16)r.x; bv.y = (__bf16)r.y; bv.z = (__bf16)r.z; bv.w = (__bf16)r.w;
        *(bf16x4*)(lo + c) = bv;
    }
}

// ---------------- GEMM1 (256^2, R4 core): h = gelu(li@W1^T + b1) ----------
__global__ __launch_bounds__(512, 2) void gemm1k(
    const bf16_t* __restrict__ A,   // [M][K]
    const bf16_t* __restrict__ Bm,  // [N][K]
    const float* __restrict__ bias, // [N]
    bf16_t* __restrict__ Cout,
    const int M, const int N, const int K)
{
    __shared__ __align__(16) char lds[131072];
    const int tid = threadIdx.x;
    const int lane = tid & 63;
    const int w = tid >> 6;
    const int wr = w >> 2;
    const int wc = w & 3;

    long tm, tn;
    tile_swz(blockIdx.x, tm, tn);

    const int NT = K >> 6;

    const int rsel = lane & 15;
    const int ko = (lane >> 4) * 8;
    const int lane_off = rsel * 64 + ((ko ^ (((rsel >> 1) & 3) << 3)) << 1);

    const char* Abytes = (const char*)A;
    const char* Bbytes = (const char*)Bm;
    size_t asrc[2][2], bsrc[2][2];
#pragma unroll
    for (int i = 0; i < 2; ++i) {
        const int d = i * 8192 + tid * 16;
        {
            const int awr = d >> 13, rem = d & 8191;
            const int sub = rem >> 10, rs = sub >> 1, ksub = sub & 1;
            const int rr = (rem >> 6) & 15;
            const int kk = ((rem & 63) >> 1) ^ (((rr >> 1) & 3) << 3);
            const int k = ksub * 32 + kk;
#pragma unroll
            for (int mq = 0; mq < 2; ++mq) {
                const long grow = tm + awr * 128 + mq * 64 + rs * 16 + rr;
                asrc[mq][i] = ((size_t)grow * K + k) * 2;
            }
        }
        {
            const int bwc = d >> 12, rem = d & 4095;
            const int sub = rem >> 10, rs = sub >> 1, ksub = sub & 1;
            const int rr = (rem >> 6) & 15;
            const int kk = ((rem & 63) >> 1) ^ (((rr >> 1) & 3) << 3);
            const int k = ksub * 32 + kk;
#pragma unroll
            for (int np = 0; np < 2; ++np) {
                const long grow = tn + bwc * 64 + np * 32 + rs * 16 + rr;
                bsrc[np][i] = ((size_t)grow * K + k) * 2;
            }
        }
    }

    auto stageA = [&](int mq, int tile, int slot) {
        const int tt = tile < NT ? tile : NT - 1;
        char* dst = lds + slot * 65536 + mq * 16384 + w * 1024;
        gload_lds16(Abytes + asrc[mq][0] + (size_t)tt * 128, dst);
        gload_lds16(Abytes + asrc[mq][1] + (size_t)tt * 128, dst + 8192);
    };
    auto stageB = [&](int np, int tile, int slot) {
        const int tt = tile < NT ? tile : NT - 1;
        char* dst = lds + slot * 65536 + 32768 + np * 16384 + w * 1024;
        gload_lds16(Bbytes + bsrc[np][0] + (size_t)tt * 128, dst);
        gload_lds16(Bbytes + bsrc[np][1] + (size_t)tt * 128, dst + 8192);
    };

    const char* aB = lds + wr * 8192;
    const char* bB = lds + 32768 + wc * 4096;

    f32x4 acc[8][4];
#pragma unroll
    for (int m = 0; m < 8; ++m)
#pragma unroll
        for (int n = 0; n < 4; ++n) acc[m][n] = (f32x4){0.f, 0.f, 0.f, 0.f};

    bf16x8 aR[4][2], b01[2][2], b23[2][2];

    stageA(0, 0, 0); stageB(0, 0, 0); stageB(1, 0, 0); stageA(1, 0, 0);
    stageA(0, 1, 1); stageB(0, 1, 1); stageB(1, 1, 1);
    asm volatile("s_waitcnt vmcnt(6)" ::: "memory");
    __builtin_amdgcn_s_barrier();

    for (int t = 0; t < NT; ++t) {
        const int s = t & 1;
        const char* aS = aB + s * 65536;
        const char* bS = bB + s * 65536;
#pragma unroll
        for (int mf = 0; mf < 4; ++mf)
#pragma unroll
            for (int ks = 0; ks < 2; ++ks)
                aR[mf][ks] = *(const bf16x8*)(aS + (mf * 2 + ks) * 1024 + lane_off);
#pragma unroll
        for (int nf = 0; nf < 2; ++nf)
#pragma unroll
            for (int ks = 0; ks < 2; ++ks)
                b01[nf][ks] = *(const bf16x8*)(bS + (nf * 2 + ks) * 1024 + lane_off);
        stageA(1, t + 1, s ^ 1);
        __builtin_amdgcn_s_setprio(1);
#pragma unroll
        for (int mf = 0; mf < 4; ++mf)
#pragma unroll
            for (int nf = 0; nf < 2; ++nf)
#pragma unroll
                for (int ks = 0; ks < 2; ++ks)
                    acc[mf][nf] = __builtin_amdgcn_mfma_f32_16x16x32_bf16(aR[mf][ks], b01[nf][ks], acc[mf][nf], 0, 0, 0);
        __builtin_amdgcn_s_setprio(0);
        __builtin_amdgcn_s_barrier();
#pragma unroll
        for (int nf = 0; nf < 2; ++nf)
#pragma unroll
            for (int ks = 0; ks < 2; ++ks)
                b23[nf][ks] = *(const bf16x8*)(bS + 16384 + (nf * 2 + ks) * 1024 + lane_off);
        stageA(0, t + 2, s);
        __builtin_amdgcn_s_setprio(1);
#pragma unroll
        for (int mf = 0; mf < 4; ++mf)
#pragma unroll
            for (int nf = 0; nf < 2; ++nf)
#pragma unroll
                for (int ks = 0; ks < 2; ++ks)
                    acc[mf][2 + nf] = __builtin_amdgcn_mfma_f32_16x16x32_bf16(aR[mf][ks], b23[nf][ks], acc[mf][2 + nf], 0, 0, 0);
        __builtin_amdgcn_s_setprio(0);
        __builtin_amdgcn_s_barrier();
#pragma unroll
        for (int mf = 0; mf < 4; ++mf)
#pragma unroll
            for (int ks = 0; ks < 2; ++ks)
                aR[mf][ks] = *(const bf16x8*)(aS + 16384 + (mf * 2 + ks) * 1024 + lane_off);
        stageB(0, t + 2, s);
        __builtin_amdgcn_s_setprio(1);
#pragma unroll
        for (int mf = 0; mf < 4; ++mf)
#pragma unroll
            for (int nf = 0; nf < 2; ++nf)
#pragma unroll
                for (int ks = 0; ks < 2; ++ks)
                    acc[4 + mf][2 + nf] = __builtin_amdgcn_mfma_f32_16x16x32_bf16(aR[mf][ks], b23[nf][ks], acc[4 + mf][2 + nf], 0, 0, 0);
        __builtin_amdgcn_s_setprio(0);
        __builtin_amdgcn_s_barrier();
        stageB(1, t + 2, s);
        asm volatile("s_waitcnt vmcnt(6)" ::: "memory");
        __builtin_amdgcn_s_setprio(1);
#pragma unroll
        for (int mf = 0; mf < 4; ++mf)
#pragma unroll
            for (int nf = 0; nf < 2; ++nf)
#pragma unroll
                for (int ks = 0; ks < 2; ++ks)
                    acc[4 + mf][nf] = __builtin_amdgcn_mfma_f32_16x16x32_bf16(aR[mf][ks], b01[nf][ks], acc[4 + mf][nf], 0, 0, 0);
        __builtin_amdgcn_s_setprio(0);
        __builtin_amdgcn_s_barrier();
    }

#pragma unroll
    for (int mq = 0; mq < 2; ++mq)
#pragma unroll
        for (int mf = 0; mf < 4; ++mf) {
            const long rbase = tm + wr * 128 + mq * 64 + mf * 16 + (lane >> 4) * 4;
#pragma unroll
            for (int np = 0; np < 2; ++np)
#pragma unroll
                for (int nf = 0; nf < 2; ++nf) {
                    const long cg = tn + wc * 64 + np * 32 + nf * 16 + rsel;
                    const float bv = __ldg(&bias[cg]);
                    const f32x4 v4 = acc[mq * 4 + mf][np * 2 + nf];
#pragma unroll
                    for (int j = 0; j < 4; ++j) {
                        const float v = v4[j] + bv;
                        const float ge = 0.5f * v * (1.0f + erff(v * 0.70710678118654752f));
                        Cout[(size_t)(rbase + j) * N + cg] = (__bf16)ge;
                    }
                }
        }
}

// ---------------- GEMM2 (256^2, R4 core) + fused final remix epilogue ----
__global__ __launch_bounds__(512, 2) void gemm2f(
    const bf16_t* __restrict__ A,   // h [M][K]
    const bf16_t* __restrict__ Bm,  // W2 [N][K]
    const float* __restrict__ bias, // b2 [N]
    float* __restrict__ outp,       // [M][4][2048]
    const int M, const int N, const int K,
    const float* __restrict__ xg,
    const float* __restrict__ hpost_g,
    const float* __restrict__ Hm_g)
{
    __shared__ __align__(16) char lds[131072];
    const int tid = threadIdx.x;
    const int lane = tid & 63;
    const int w = tid >> 6;
    const int wr = w >> 2;
    const int wc = w & 3;

    long tm, tn;
    tile_swz(blockIdx.x, tm, tn);

    const int NT = K >> 6;

    const int rsel = lane & 15;
    const int ko = (lane >> 4) * 8;
    const int lane_off = rsel * 64 + ((ko ^ (((rsel >> 1) & 3) << 3)) << 1);

    const char* Abytes = (const char*)A;
    const char* Bbytes = (const char*)Bm;
    size_t asrc[2][2], bsrc[2][2];
#pragma unroll
    for (int i = 0; i < 2; ++i) {
        const int d = i * 8192 + tid * 16;
        {
            const int awr = d >> 13, rem = d & 8191;
            const int sub = rem >> 10, rs = sub >> 1, ksub = sub & 1;
            const int rr = (rem >> 6) & 15;
            const int kk = ((rem & 63) >> 1) ^ (((rr >> 1) & 3) << 3);
            const int k = ksub * 32 + kk;
#pragma unroll
            for (int mq = 0; mq < 2; ++mq) {
                const long grow = tm + awr * 128 + mq * 64 + rs * 16 + rr;
                asrc[mq][i] = ((size_t)grow * K + k) * 2;
            }
        }
        {
            const int bwc = d >> 12, rem = d & 4095;
            const int sub = rem >> 10, rs = sub >> 1, ksub = sub & 1;
            const int rr = (rem >> 6) & 15;
            const int kk = ((rem & 63) >> 1) ^ (((rr >> 1) & 3) << 3);
            const int k = ksub * 32 + kk;
#pragma unroll
            for (int np = 0; np < 2; ++np) {
                const long grow = tn + bwc * 64 + np * 32 + rs * 16 + rr;
                bsrc[np][i] = ((size_t)grow * K + k) * 2;
            }
        }
    }

    auto stageA = [&](int mq, int tile, int slot) {
        const int tt = tile < NT ? tile : NT - 1;
        char* dst = lds + slot * 65536 + mq * 16384 + w * 1024;
        gload_lds16(Abytes + asrc[mq][0] + (size_t)tt * 128, dst);
        gload_lds16(Abytes + asrc[mq][1] + (size_t)tt * 128, dst + 8192);
    };
    auto stageB = [&](int np, int tile, int slot) {
        const int tt = tile < NT ? tile : NT - 1;
        char* dst = lds + slot * 65536 + 32768 + np * 16384 + w * 1024;
        gload_lds16(Bbytes + bsrc[np][0] + (size_t)tt * 128, dst);
        gload_lds16(Bbytes + bsrc[np][1] + (size_t)tt * 128, dst + 8192);
    };

    const char* aB = lds + wr * 8192;
    const char* bB = lds + 32768 + wc * 4096;

    f32x4 acc[8][4];
#pragma unroll
    for (int m = 0; m < 8; ++m)
#pragma unroll
        for (int n = 0; n < 4; ++n) acc[m][n] = (f32x4){0.f, 0.f, 0.f, 0.f};

    bf16x8 aR[4][2], b01[2][2], b23[2][2];

    stageA(0, 0, 0); stageB(0, 0, 0); stageB(1, 0, 0); stageA(1, 0, 0);
    stageA(0, 1, 1); stageB(0, 1, 1); stageB(1, 1, 1);
    asm volatile("s_waitcnt vmcnt(6)" ::: "memory");
    __builtin_amdgcn_s_barrier();

    for (int t = 0; t < NT; ++t) {
        const int s = t & 1;
        const char* aS = aB + s * 65536;
        const char* bS = bB + s * 65536;
#pragma unroll
        for (int mf = 0; mf < 4; ++mf)
#pragma unroll
            for (int ks = 0; ks < 2; ++ks)
                aR[mf][ks] = *(const bf16x8*)(aS + (mf * 2 + ks) * 1024 + lane_off);
#pragma unroll
        for (int nf = 0; nf < 2; ++nf)
#pragma unroll
            for (int ks = 0; ks < 2; ++ks)
                b01[nf][ks] = *(const bf16x8*)(bS + (nf * 2 + ks) * 1024 + lane_off);
        stageA(1, t + 1, s ^ 1);
        __builtin_amdgcn_s_setprio(1);
#pragma unroll
        for (int mf = 0; mf < 4; ++mf)
#pragma unroll
            for (int nf = 0; nf < 2; ++nf)
#pragma unroll
                for (int ks = 0; ks < 2; ++ks)
                    acc[mf][nf] = __builtin_amdgcn_mfma_f32_16x16x32_bf16(aR[mf][ks], b01[nf][ks], acc[mf][nf], 0, 0, 0);
        __builtin_amdgcn_s_setprio(0);
        __builtin_amdgcn_s_barrier();
#pragma unroll
        for (int nf = 0; nf < 2; ++nf)
#pragma unroll
            for (int ks = 0; ks < 2; ++ks)
                b23[nf][ks] = *(const bf16x8*)(bS + 16384 + (nf * 2 + ks) * 1024 + lane_off);
        stageA(0, t + 2, s);
        __builtin_amdgcn_s_setprio(1);
#pragma unroll
        for (int mf = 0; mf < 4; ++mf)
#pragma unroll
            for (int nf = 0; nf < 2; ++nf)
#pragma unroll
                for (int ks = 0; ks < 2; ++ks)
                    acc[mf][2 + nf] = __builtin_amdgcn_mfma_f32_16x16x32_bf16(aR[mf][ks], b23[nf][ks], acc[mf][2 + nf], 0, 0, 0);
        __builtin_amdgcn_s_setprio(0);
        __builtin_amdgcn_s_barrier();
#pragma unroll
        for (int mf = 0; mf < 4; ++mf)
#pragma unroll
            for (int ks = 0; ks < 2; ++ks)
                aR[mf][ks] = *(const bf16x8*)(aS + 16384 + (mf * 2 + ks) * 1024 + lane_off);
        stageB(0, t + 2, s);
        __builtin_amdgcn_s_setprio(1);
#pragma unroll
        for (int mf = 0; mf < 4; ++mf)
#pragma unroll
            for (int nf = 0; nf < 2; ++nf)
#pragma unroll
                for (int ks = 0; ks < 2; ++ks)
                    acc[4 + mf][2 + nf] = __builtin_amdgcn_mfma_f32_16x16x32_bf16(aR[mf][ks], b23[nf][ks], acc[4 + mf][2 + nf], 0, 0, 0);
        __builtin_amdgcn_s_setprio(0);
        __builtin_amdgcn_s_barrier();
        stageB(1, t + 2, s);
        asm volatile("s_waitcnt vmcnt(6)" ::: "memory");
        __builtin_amdgcn_s_setprio(1);
#pragma unroll
        for (int mf = 0; mf < 4; ++mf)
#pragma unroll
            for (int nf = 0; nf < 2; ++nf)
#pragma unroll
                for (int ks = 0; ks < 2; ++ks)
                    acc[4 + mf][nf] = __builtin_amdgcn_mfma_f32_16x16x32_bf16(aR[mf][ks], b01[nf][ks], acc[4 + mf][nf], 0, 0, 0);
        __builtin_amdgcn_s_setprio(0);
        __builtin_amdgcn_s_barrier();
    }

    // fused final remix epilogue (plain stores: NT stores caused partial-line
    // write amplification in R11 — WRITE 264->322 MB, +25us)
#pragma unroll
    for (int mq = 0; mq < 2; ++mq)
#pragma unroll
        for (int mf = 0; mf < 4; ++mf) {
            const long rbase = tm + wr * 128 + mq * 64 + mf * 16 + (lane >> 4) * 4;
#pragma unroll
            for (int j = 0; j < 4; ++j) {
                const long tok = rbase + j;
                float H[16], hq[4];
#pragma unroll
                for (int z = 0; z < 16; ++z) H[z] = __ldg(&Hm_g[tok * 16 + z]);
#pragma unroll
                for (int z = 0; z < 4; ++z) hq[z] = __ldg(&hpost_g[tok * 4 + z]);
                const float* xrow = xg + (size_t)tok * (size_t)NC_DIM;
                float* orow = outp + (size_t)tok * (size_t)NC_DIM;
#pragma unroll
                for (int np = 0; np < 2; ++np)
#pragma unroll
                    for (int nf = 0; nf < 2; ++nf) {
                        const long cg = tn + wc * 64 + np * 32 + nf * 16 + rsel;
                        const float lo = acc[mq * 4 + mf][np * 2 + nf][j] + __ldg(&bias[cg]);
                        const float x0 = xrow[cg];
                        const float x1 = xrow[2048 + cg];
                        const float x2 = xrow[4096 + cg];
                        const float x3 = xrow[6144 + cg];
#pragma unroll
                        for (int i = 0; i < 4; ++i)
                            orow[i * 2048 + cg] =
                                H[i * 4 + 0] * x0 + H[i * 4 + 1] * x1 +
                                H[i * 4 + 2] * x2 + H[i * 4 + 3] * x3 + hq[i] * lo;
                    }
            }
        }
}

extern "C" void kernel_launch(void* const* d_in, const int* in_sizes, int n_in,
                              void* d_out, int out_size, void* d_ws, size_t ws_size,
                              hipStream_t stream) {
    const float* x     = (const float*)d_in[0];
    const float* Wall  = (const float*)d_in[1];
    const float* ball  = (const float*)d_in[2];
    const float* apre  = (const float*)d_in[3];
    const float* apost = (const float*)d_in[4];
    const float* ares  = (const float*)d_in[5];
    const float* W1    = (const float*)d_in[6];
    const float* b1    = (const float*)d_in[7];
    const float* W2    = (const float*)d_in[8];
    const float* b2    = (const float*)d_in[9];
    const float* perm  = (const float*)d_in[10];
    float* out = (float*)d_out;
    char* ws = (char*)d_ws;

    // workspace layout (bytes)
    bf16_t* W1b  = (bf16_t*)(ws);                  //  32 MB  [8192][2048]
    bf16_t* W2b  = (bf16_t*)(ws + 33554432ull);    //  32 MB  [2048][8192]
    bf16_t* li   = (bf16_t*)(ws + 67108864ull);    //  32 MB  [8192][2048]
    bf16_t* h    = (bf16_t*)(ws + 100663296ull);   // 128 MB  [8192][8192]
    float*  hpost= (float*)(ws + 302120960ull);    // 128 KB  [8192][4]
    float*  Hm   = (float*)(ws + 302252032ull);    // 512 KB  [8192][16]

    cvt_f32_bf16<<<2048, 256, 0, stream>>>(W1, W1b, 16777216 / 4);
    cvt_f32_bf16<<<2048, 256, 0, stream>>>(W2, W2b, 16777216 / 4);
    k_proj<<<256, 256, 0, stream>>>(x, Wall, ball, apre, apost, ares, perm, hpost, Hm, li);
    gemm1k<<<1024, 512, 0, stream>>>(li, W1b, b1, h, 8192, 8192, 2048);
    gemm2f<<<256, 512, 0, stream>>>(h, W2b, b2, out, 8192, 2048, 8192,
                                    x, hpost, Hm);
}